// Round 1
// baseline (1091.863 us; speedup 1.0000x reference)
//
#include <hip/hip_runtime.h>
#include <math.h>

typedef __attribute__((ext_vector_type(8))) short short8;
typedef __attribute__((ext_vector_type(4))) short shortx4;
typedef __attribute__((ext_vector_type(4))) int   intx4;
typedef __attribute__((ext_vector_type(4))) float floatx4;

#define BQ 256   // B
#define SQ 256   // S
#define DQ 256   // D
#define HQ 4
#define DHQ 64

__device__ __forceinline__ short f2bf(float f) {
  union { float f; unsigned u; } c; c.f = f;
  unsigned r = c.u + 0x7fffu + ((c.u >> 16) & 1u);
  return (short)(r >> 16);
}
__device__ __forceinline__ float bf2f(short s) {
  union { unsigned u; float f; } c; c.u = ((unsigned)(unsigned short)s) << 16;
  return c.f;
}

// ---------------- weight convert + transpose: W[L,K,N] f32 -> Wt[L,N,K] bf16 --------
__global__ __launch_bounds__(256) void wconv_kernel(const float* __restrict__ W,
    short* __restrict__ Wt, int K, int N, int total) {
  int idx = blockIdx.x * 256 + threadIdx.x;
  if (idx >= total) return;
  int nk = N * K;
  int l = idx / nk;
  int r = idx - l * nk;
  int n = r / K;
  int k = r - n * K;
  Wt[idx] = f2bf(W[(size_t)l * nk + (size_t)k * N + n]);
}

// ---------------- embedding + LN; writes xb (bf16) and total (f32) ------------------
__global__ __launch_bounds__(256) void embed_kernel(const int* __restrict__ ids,
    const float* __restrict__ item, const float* __restrict__ pos,
    short* __restrict__ xb, float* __restrict__ tot) {
  const int tid = threadIdx.x, lane = tid & 63, w = tid >> 6;
  const int row = blockIdx.x * 4 + w;          // token index in [0, B*S)
  const int s = row & (SQ - 1);
  const int id = ids[row];
  floatx4 a = *(const floatx4*)(item + (size_t)id * DQ + lane * 4);
  floatx4 p = *(const floatx4*)(pos + (size_t)s * DQ + lane * 4);
  float v[4];
#pragma unroll
  for (int i = 0; i < 4; ++i) v[i] = a[i] + p[i];
  float sm = v[0] + v[1] + v[2] + v[3];
  float ss = v[0]*v[0] + v[1]*v[1] + v[2]*v[2] + v[3]*v[3];
#pragma unroll
  for (int off = 32; off; off >>= 1) { sm += __shfl_xor(sm, off); ss += __shfl_xor(ss, off); }
  float mu = sm * (1.0f / DQ);
  float var = ss * (1.0f / DQ) - mu * mu;
  float rs = rsqrtf(var + 1e-5f);
  shortx4 o; floatx4 y;
#pragma unroll
  for (int i = 0; i < 4; ++i) { y[i] = (v[i] - mu) * rs; o[i] = f2bf(y[i]); }
  *(shortx4*)(xb + (size_t)row * DQ + lane * 4) = o;
  *(floatx4*)(tot + (size_t)row * DQ + lane * 4) = y;
}

// ---------------- LN: in bf16 [M,256] -> xout bf16; optional tot += -----------------
__global__ __launch_bounds__(256) void ln_kernel(const short* __restrict__ in,
    short* __restrict__ xout, float* __restrict__ tot) {
  const int tid = threadIdx.x, lane = tid & 63, w = tid >> 6;
  const int row = blockIdx.x * 4 + w;
  shortx4 sv = *(const shortx4*)(in + (size_t)row * DQ + lane * 4);
  float v[4];
#pragma unroll
  for (int i = 0; i < 4; ++i) v[i] = bf2f(sv[i]);
  float sm = v[0] + v[1] + v[2] + v[3];
  float ss = v[0]*v[0] + v[1]*v[1] + v[2]*v[2] + v[3]*v[3];
#pragma unroll
  for (int off = 32; off; off >>= 1) { sm += __shfl_xor(sm, off); ss += __shfl_xor(ss, off); }
  float mu = sm * (1.0f / DQ);
  float var = ss * (1.0f / DQ) - mu * mu;
  float rs = rsqrtf(var + 1e-5f);
  shortx4 o; float y[4];
#pragma unroll
  for (int i = 0; i < 4; ++i) { y[i] = (v[i] - mu) * rs; o[i] = f2bf(y[i]); }
  *(shortx4*)(xout + (size_t)row * DQ + lane * 4) = o;
  if (tot) {
    floatx4* tp = (floatx4*)(tot + (size_t)row * DQ + lane * 4);
    floatx4 t = *tp;
#pragma unroll
    for (int i = 0; i < 4; ++i) t[i] += y[i];
    *tp = t;
  }
}

// ---------------- bf16 MFMA GEMM: out[M,N] = A[M,K] @ Wt[N,K]^T + bias (+res)(+gelu)
__device__ __forceinline__ void async16(const void* g, void* l) {
  __builtin_amdgcn_global_load_lds(
      (const __attribute__((address_space(1))) void*)g,
      (__attribute__((address_space(3))) void*)l, 16, 0, 0);
}

__global__ __launch_bounds__(256) void gemm_kernel(
    const short* __restrict__ A, const short* __restrict__ Bt,
    const float* __restrict__ bias, const short* __restrict__ res,
    short* __restrict__ out, int M, int N, int K, int act) {
  __shared__ short As[128 * 32];
  __shared__ short Bs[128 * 32];
  const int tid = threadIdx.x, lane = tid & 63, w = tid >> 6;
  const int lane15 = lane & 15, quad = lane >> 4;
  const int wm = w & 1, wn = w >> 1;
  const int bm = blockIdx.y, bn = blockIdx.x;
  const short* Ab = A + (size_t)bm * 128 * K;
  const short* Bb = Bt + (size_t)bn * 128 * K;
  floatx4 acc[4][4] = {};
  const int nk = K >> 5;
  const int rA = lane >> 2;          // 0..15 within 16-row chunk
  const int cA = (lane & 3) * 8;     // 0,8,16,24
  for (int kb = 0; kb < nk; ++kb) {
    const int k0 = kb * 32;
#pragma unroll
    for (int c2 = 0; c2 < 2; ++c2) {
      int c = 2 * w + c2;
      int row = c * 16 + rA;
      async16(Ab + (size_t)row * K + k0 + cA, &As[c * 512]);
      async16(Bb + (size_t)row * K + k0 + cA, &Bs[c * 512]);
    }
    __syncthreads();
    short8 af[4], bf[4];
#pragma unroll
    for (int i = 0; i < 4; ++i) {
      af[i] = *(const short8*)&As[(wm * 64 + i * 16 + lane15) * 32 + quad * 8];
      bf[i] = *(const short8*)&Bs[(wn * 64 + i * 16 + lane15) * 32 + quad * 8];
    }
#pragma unroll
    for (int i = 0; i < 4; ++i)
#pragma unroll
      for (int j = 0; j < 4; ++j)
        acc[i][j] = __builtin_amdgcn_mfma_f32_16x16x32_bf16(af[i], bf[j], acc[i][j], 0, 0, 0);
    __syncthreads();
  }
#pragma unroll
  for (int i = 0; i < 4; ++i) {
#pragma unroll
    for (int j = 0; j < 4; ++j) {
      int n = bn * 128 + wn * 64 + j * 16 + lane15;
      float bs = bias ? bias[n] : 0.0f;
#pragma unroll
      for (int r = 0; r < 4; ++r) {
        int m = bm * 128 + wm * 64 + i * 16 + quad * 4 + r;
        float v = acc[i][j][r] + bs;
        if (res) v += bf2f(res[(size_t)m * N + n]);
        if (act) v = 0.5f * v * (1.0f + erff(v * 0.70710678118654752f));
        out[(size_t)m * N + n] = f2bf(v);
      }
    }
  }
}

// ---------------- fused attention: one block per (b, h, 64 q-rows) ------------------
// LDS: K in k-block-major [2][256][32] (32KB) ; Vt [8][64][32] (32KB); P aliases K.
__global__ __launch_bounds__(256) void attn_kernel(
    const short* __restrict__ qg, const short* __restrict__ kg, const short* __restrict__ vg,
    const int* __restrict__ ids, short* __restrict__ ctxg) {
  __shared__ short lds[32768];
  const int tid = threadIdx.x, lane = tid & 63, w = tid >> 6;
  const int lane15 = lane & 15, quad = lane >> 4;
  const int bx = blockIdx.x;
  const int qt = bx & 3, h = (bx >> 2) & 3, b = bx >> 4;
  const int base_row = b * SQ;
  const int hcol = h * DHQ;

  // stage K (k-block-major) and V^T (k-block-major)
  for (int it = 0; it < 8; ++it) {
    int s = it * 32 + (tid >> 3);
    int d0 = (tid & 7) * 8;
    size_t goff = (size_t)(base_row + s) * DQ + hcol + d0;
    intx4 kv = *(const intx4*)(kg + goff);
    *(intx4*)&lds[(d0 >> 5) * 8192 + s * 32 + (d0 & 31)] = kv;
    short8 vv = *(const short8*)(vg + goff);
    int vb0 = 16384 + (s >> 5) * 2048 + (s & 31);
#pragma unroll
    for (int i = 0; i < 8; ++i) lds[vb0 + (d0 + i) * 32] = vv[i];
  }
  __syncthreads();

  // Q fragments straight from global
  const int q0 = qt * 64 + w * 16;
  short8 qf[2];
#pragma unroll
  for (int ks = 0; ks < 2; ++ks)
    qf[ks] = *(const short8*)(qg + (size_t)(base_row + q0 + lane15) * DQ + hcol + ks * 32 + quad * 8);

  // scores: 16 q-rows x 256 keys
  float sc[16][4];
#pragma unroll
  for (int t = 0; t < 16; ++t) {
    floatx4 a = {0.f, 0.f, 0.f, 0.f};
#pragma unroll
    for (int ks = 0; ks < 2; ++ks) {
      short8 bfr = *(const short8*)&lds[ks * 8192 + (t * 16 + lane15) * 32 + quad * 8];
      a = __builtin_amdgcn_mfma_f32_16x16x32_bf16(qf[ks], bfr, a, 0, 0, 0);
    }
    int kk = t * 16 + lane15;
    int padv = ids[base_row + kk];
#pragma unroll
    for (int r = 0; r < 4; ++r) {
      int q = q0 + quad * 4 + r;
      float bias = (padv > 0 && kk <= q) ? 0.0f : -10000.0f;
      sc[t][r] = a[r] * 0.125f + bias;
    }
  }
  __syncthreads();  // all waves done reading K -> can overwrite with P

  // softmax per row, write P (bf16) into per-wave LDS region (aliases K)
#pragma unroll
  for (int r = 0; r < 4; ++r) {
    float m = -1e30f;
#pragma unroll
    for (int t = 0; t < 16; ++t) m = fmaxf(m, sc[t][r]);
    m = fmaxf(m, __shfl_xor(m, 1)); m = fmaxf(m, __shfl_xor(m, 2));
    m = fmaxf(m, __shfl_xor(m, 4)); m = fmaxf(m, __shfl_xor(m, 8));
    float l = 0.0f;
#pragma unroll
    for (int t = 0; t < 16; ++t) { sc[t][r] = __expf(sc[t][r] - m); l += sc[t][r]; }
    l += __shfl_xor(l, 1); l += __shfl_xor(l, 2);
    l += __shfl_xor(l, 4); l += __shfl_xor(l, 8);
    float inv = 1.0f / l;
#pragma unroll
    for (int t = 0; t < 16; ++t)
      lds[w * 4096 + (t >> 1) * 512 + (quad * 4 + r) * 32 + (t & 1) * 16 + lane15] =
          f2bf(sc[t][r] * inv);
  }
  __syncthreads();

  // ctx = P @ V : [16 x 256] @ [256 x 64]
  floatx4 o[4] = {};
#pragma unroll
  for (int kb = 0; kb < 8; ++kb) {
    short8 pf = *(const short8*)&lds[w * 4096 + kb * 512 + lane15 * 32 + quad * 8];
#pragma unroll
    for (int dt = 0; dt < 4; ++dt) {
      short8 vf = *(const short8*)&lds[16384 + kb * 2048 + (dt * 16 + lane15) * 32 + quad * 8];
      o[dt] = __builtin_amdgcn_mfma_f32_16x16x32_bf16(pf, vf, o[dt], 0, 0, 0);
    }
  }
#pragma unroll
  for (int dt = 0; dt < 4; ++dt)
#pragma unroll
    for (int r = 0; r < 4; ++r) {
      int q = q0 + quad * 4 + r;
      ctxg[(size_t)(base_row + q) * DQ + hcol + dt * 16 + lane15] = f2bf(o[dt][r]);
    }
}

extern "C" void kernel_launch(void* const* d_in, const int* in_sizes, int n_in,
                              void* d_out, int out_size, void* d_ws, size_t ws_size,
                              hipStream_t stream) {
  const int*   ids  = (const int*)d_in[0];
  const float* item = (const float*)d_in[1];
  const float* pos  = (const float*)d_in[2];
  const float* Wq = (const float*)d_in[3];  const float* bq = (const float*)d_in[4];
  const float* Wk = (const float*)d_in[5];  const float* bk = (const float*)d_in[6];
  const float* Wv = (const float*)d_in[7];  const float* bv = (const float*)d_in[8];
  const float* Wo = (const float*)d_in[9];  const float* bo = (const float*)d_in[10];
  const float* W1 = (const float*)d_in[11]; const float* b1 = (const float*)d_in[12];
  const float* W2 = (const float*)d_in[13]; const float* b2 = (const float*)d_in[14];
  float* out = (float*)d_out;

  const size_t EL = (size_t)BQ * SQ * DQ;  // 16,777,216
  short* qb   = (short*)d_ws;
  short* kb   = qb + EL;
  short* vb   = kb + EL;
  short* ctxb = vb + EL;
  short* gb   = qb;                 // aliases q/k/v/ctx region (4*EL bf16)
  short* xb   = ctxb + EL;
  short* hb   = xb + EL;
  short* tmp  = hb + EL;
  short* WqT  = tmp + EL;
  short* WkT  = WqT + 2 * DQ * DQ;
  short* WvT  = WkT + 2 * DQ * DQ;
  short* WoT  = WvT + 2 * DQ * DQ;
  short* W1T  = WoT + 2 * DQ * DQ;
  short* W2T  = W1T + 2 * DQ * 4 * DQ;

  const int M = BQ * SQ;            // 65536
  const int tDD = 2 * DQ * DQ;      // 131072
  const int tDF = 2 * DQ * 4 * DQ;  // 524288

  wconv_kernel<<<tDD / 256, 256, 0, stream>>>(Wq, WqT, DQ, DQ, tDD);
  wconv_kernel<<<tDD / 256, 256, 0, stream>>>(Wk, WkT, DQ, DQ, tDD);
  wconv_kernel<<<tDD / 256, 256, 0, stream>>>(Wv, WvT, DQ, DQ, tDD);
  wconv_kernel<<<tDD / 256, 256, 0, stream>>>(Wo, WoT, DQ, DQ, tDD);
  wconv_kernel<<<tDF / 256, 256, 0, stream>>>(W1, W1T, DQ, 4 * DQ, tDF);
  wconv_kernel<<<tDF / 256, 256, 0, stream>>>(W2, W2T, 4 * DQ, DQ, tDF);

  embed_kernel<<<M / 4, 256, 0, stream>>>(ids, item, pos, xb, out);

  for (int l = 0; l < 2; ++l) {
    gemm_kernel<<<dim3(2, M / 128), 256, 0, stream>>>(xb, WqT + l * DQ * DQ, bq + l * DQ,
                                                      nullptr, qb, M, DQ, DQ, 0);
    gemm_kernel<<<dim3(2, M / 128), 256, 0, stream>>>(xb, WkT + l * DQ * DQ, bk + l * DQ,
                                                      nullptr, kb, M, DQ, DQ, 0);
    gemm_kernel<<<dim3(2, M / 128), 256, 0, stream>>>(xb, WvT + l * DQ * DQ, bv + l * DQ,
                                                      nullptr, vb, M, DQ, DQ, 0);
    attn_kernel<<<BQ * HQ * (SQ / 64), 256, 0, stream>>>(qb, kb, vb, ids, ctxb);
    gemm_kernel<<<dim3(2, M / 128), 256, 0, stream>>>(ctxb, WoT + l * DQ * DQ, bo + l * DQ,
                                                      xb, tmp, M, DQ, DQ, 0);
    ln_kernel<<<M / 4, 256, 0, stream>>>(tmp, hb, nullptr);
    gemm_kernel<<<dim3(8, M / 128), 256, 0, stream>>>(hb, W1T + l * DQ * 4 * DQ, b1 + l * 4 * DQ,
                                                      nullptr, gb, M, 4 * DQ, DQ, 1);
    gemm_kernel<<<dim3(2, M / 128), 256, 0, stream>>>(gb, W2T + l * DQ * 4 * DQ, b2 + l * DQ,
                                                      nullptr, tmp, M, DQ, 4 * DQ, 0);
    ln_kernel<<<M / 4, 256, 0, stream>>>(tmp, xb, out);
  }
}

// Round 2
// 815.286 us; speedup vs baseline: 1.3392x; 1.3392x over previous
//
#include <hip/hip_runtime.h>
#include <math.h>

typedef __attribute__((ext_vector_type(8))) short short8;
typedef __attribute__((ext_vector_type(4))) short shortx4;
typedef __attribute__((ext_vector_type(4))) int   intx4;
typedef __attribute__((ext_vector_type(4))) float floatx4;

#define BQ 256
#define SQ 256
#define DQ 256
#define HQ 4
#define DHQ 64

__device__ __forceinline__ short f2bf(float f) {
  union { float f; unsigned u; } c; c.f = f;
  unsigned r = c.u + 0x7fffu + ((c.u >> 16) & 1u);
  return (short)(r >> 16);
}
__device__ __forceinline__ float bf2f(short s) {
  union { unsigned u; float f; } c; c.u = ((unsigned)(unsigned short)s) << 16;
  return c.f;
}
__device__ __forceinline__ float gelu_fast(float x) {
  float t = x * (0.7978845608f + 0.0356774081f * x * x);  // 2t/2 form folded
  return x / (1.0f + __expf(-2.0f * t));
}

// ---------------- weight convert + transpose: W[L,K,N] f32 -> Wt[L,N,K] bf16 --------
__global__ __launch_bounds__(256) void wconv_kernel(const float* __restrict__ W,
    short* __restrict__ Wt, int K, int N, int total) {
  int idx = blockIdx.x * 256 + threadIdx.x;
  if (idx >= total) return;
  int nk = N * K;
  int l = idx / nk;
  int r = idx - l * nk;
  int n = r / K;
  int k = r - n * K;
  Wt[idx] = f2bf(W[(size_t)l * nk + (size_t)k * N + n]);
}

// ---------------- concat q/k/v biases: dst[l][768] --------------------------------
__global__ __launch_bounds__(256) void bconv_kernel(const float* __restrict__ bq,
    const float* __restrict__ bk, const float* __restrict__ bv, float* __restrict__ dst) {
  int i = blockIdx.x * 256 + threadIdx.x;   // 0..1535
  int l = i / 768, r = i - l * 768;
  const float* src = (r < 256) ? bq : ((r < 512) ? bk : bv);
  dst[i] = src[l * 256 + (r & 255)];
}

// ---------------- embedding + LN; writes xb (bf16) and total (f32) ------------------
__global__ __launch_bounds__(256) void embed_kernel(const int* __restrict__ ids,
    const float* __restrict__ item, const float* __restrict__ pos,
    short* __restrict__ xb, float* __restrict__ tot) {
  const int tid = threadIdx.x, lane = tid & 63, w = tid >> 6;
  const int row = blockIdx.x * 4 + w;
  const int s = row & (SQ - 1);
  const int id = ids[row];
  floatx4 a = *(const floatx4*)(item + (size_t)id * DQ + lane * 4);
  floatx4 p = *(const floatx4*)(pos + (size_t)s * DQ + lane * 4);
  float v[4];
#pragma unroll
  for (int i = 0; i < 4; ++i) v[i] = a[i] + p[i];
  float sm = v[0] + v[1] + v[2] + v[3];
  float ss = v[0]*v[0] + v[1]*v[1] + v[2]*v[2] + v[3]*v[3];
#pragma unroll
  for (int off = 32; off; off >>= 1) { sm += __shfl_xor(sm, off); ss += __shfl_xor(ss, off); }
  float mu = sm * (1.0f / DQ);
  float var = ss * (1.0f / DQ) - mu * mu;
  float rs = rsqrtf(var + 1e-5f);
  shortx4 o; floatx4 y;
#pragma unroll
  for (int i = 0; i < 4; ++i) { y[i] = (v[i] - mu) * rs; o[i] = f2bf(y[i]); }
  *(shortx4*)(xb + (size_t)row * DQ + lane * 4) = o;
  *(floatx4*)(tot + (size_t)row * DQ + lane * 4) = y;
}

// ---------------- bf16 MFMA GEMM, tile 128x256, 512 threads ------------------------
// out[M,N] = A[M,K] @ Bt[N,K]^T + bias ; optional res-add, gelu, row-LN, tot += y
__device__ __forceinline__ void async16(const void* g, void* l) {
  __builtin_amdgcn_global_load_lds(
      (const __attribute__((address_space(1))) void*)g,
      (__attribute__((address_space(3))) void*)l, 16, 0, 0);
}

__global__ __launch_bounds__(512, 4) void gemm_kernel(
    const short* __restrict__ A, const short* __restrict__ Bt,
    const float* __restrict__ bias, const short* __restrict__ res,
    short* __restrict__ out, float* __restrict__ tot,
    int M, int N, int K, int act, int ln, int chunked) {
  __shared__ short smem[12288];            // As 4096 | Bs 8192 ; epilogue: Cs + red
  short* As = smem;
  short* Bs = smem + 4096;
  float* redS  = (float*)(smem + 8448);    // [128][4]
  float* redS2 = redS + 512;               // [128][4]
  const int tid = threadIdx.x, lane = tid & 63, w = tid >> 6;
  const int lane15 = lane & 15, quad = lane >> 4;
  const int wm = w & 1, wn = w >> 1;
  const int bm = blockIdx.y, bn = blockIdx.x;

  const short* Ag = A + (size_t)(bm * 128 + w * 16 + (lane >> 2)) * K + (lane & 3) * 8;
  const short* Bg0 = Bt + (size_t)(bn * 256 + w * 32 + (lane >> 2)) * K + (lane & 3) * 8;
  const short* Bg1 = Bg0 + (size_t)16 * K;

  floatx4 acc[4][4] = {};
  const int nk = K >> 5;
  for (int kb = 0; kb < nk; ++kb) {
    const int k0 = kb * 32;
    async16(Ag + k0, &As[w * 512]);
    async16(Bg0 + k0, &Bs[w * 1024]);
    async16(Bg1 + k0, &Bs[w * 1024 + 512]);
    __syncthreads();
    short8 af[4], bfr[4];
#pragma unroll
    for (int i = 0; i < 4; ++i) {
      af[i]  = *(const short8*)&As[(wm * 64 + i * 16 + lane15) * 32 + quad * 8];
      bfr[i] = *(const short8*)&Bs[(wn * 64 + i * 16 + lane15) * 32 + quad * 8];
    }
#pragma unroll
    for (int i = 0; i < 4; ++i)
#pragma unroll
      for (int j = 0; j < 4; ++j)
        // swapped operands: lane holds C[m=i*16+lane15][n=j*16+quad*4+reg]
        acc[i][j] = __builtin_amdgcn_mfma_f32_16x16x32_bf16(bfr[j], af[i], acc[i][j], 0, 0, 0);
    __syncthreads();
  }

  // ---- pass 1: z = acc + bias (+res) (+gelu); stats for LN ----
  float sum_[4], sq_[4];
#pragma unroll
  for (int i = 0; i < 4; ++i) { sum_[i] = 0.0f; sq_[i] = 0.0f; }
#pragma unroll
  for (int i = 0; i < 4; ++i) {
    size_t rowg = (size_t)bm * 128 + wm * 64 + i * 16 + lane15;
#pragma unroll
    for (int j = 0; j < 4; ++j) {
      int nloc = wn * 64 + j * 16 + quad * 4;
      floatx4 b4 = *(const floatx4*)(bias + bn * 256 + nloc);
      shortx4 r4;
      if (res) r4 = *(const shortx4*)(res + rowg * 256 + nloc);
#pragma unroll
      for (int r = 0; r < 4; ++r) {
        float z = acc[i][j][r] + b4[r];
        if (res) z += bf2f(r4[r]);
        if (act) z = gelu_fast(z);
        acc[i][j][r] = z;
        if (ln) { sum_[i] += z; sq_[i] += z * z; }
      }
    }
  }

  // ---- LN: cross-quad shuffle + cross-wave LDS reduction ----
  if (ln) {
#pragma unroll
    for (int i = 0; i < 4; ++i) {
      sum_[i] += __shfl_xor(sum_[i], 16); sum_[i] += __shfl_xor(sum_[i], 32);
      sq_[i]  += __shfl_xor(sq_[i], 16);  sq_[i]  += __shfl_xor(sq_[i], 32);
    }
    if (quad == 0) {
#pragma unroll
      for (int i = 0; i < 4; ++i) {
        int lr = wm * 64 + i * 16 + lane15;
        redS[lr * 4 + wn] = sum_[i];
        redS2[lr * 4 + wn] = sq_[i];
      }
    }
    __syncthreads();
#pragma unroll
    for (int i = 0; i < 4; ++i) {
      int lr = wm * 64 + i * 16 + lane15;
      float s = redS[lr * 4] + redS[lr * 4 + 1] + redS[lr * 4 + 2] + redS[lr * 4 + 3];
      float q = redS2[lr * 4] + redS2[lr * 4 + 1] + redS2[lr * 4 + 2] + redS2[lr * 4 + 3];
      float mu = s * (1.0f / 256.0f);
      float var = q * (1.0f / 256.0f) - mu * mu;
      float rs = rsqrtf(var + 1e-5f);
      size_t rowg = (size_t)bm * 128 + wm * 64 + i * 16 + lane15;
#pragma unroll
      for (int j = 0; j < 4; ++j) {
        int nloc = wn * 64 + j * 16 + quad * 4;
        floatx4 y;
#pragma unroll
        for (int r = 0; r < 4; ++r) y[r] = (acc[i][j][r] - mu) * rs;
        acc[i][j] = y;
        if (tot) {
          floatx4* tp = (floatx4*)(tot + rowg * 256 + nloc);
          floatx4 t = *tp;
#pragma unroll
          for (int r = 0; r < 4; ++r) t[r] += y[r];
          *tp = t;
        }
      }
    }
  }

  // ---- staged coalesced store: 4 chunks of 32 rows x 256 cols (stride 264) ----
#pragma unroll
  for (int i = 0; i < 4; ++i) {
    __syncthreads();
    int lr = wm * 16 + lane15;
#pragma unroll
    for (int j = 0; j < 4; ++j) {
      shortx4 o;
#pragma unroll
      for (int r = 0; r < 4; ++r) o[r] = f2bf(acc[i][j][r]);
      *(shortx4*)&smem[lr * 264 + wn * 64 + j * 16 + quad * 4] = o;
    }
    __syncthreads();
#pragma unroll
    for (int it = 0; it < 2; ++it) {
      int t2 = tid + it * 512;
      int lr2 = t2 >> 5, c = (t2 & 31) * 8;
      short8 v = *(const short8*)&smem[lr2 * 264 + c];
      size_t rowg = (size_t)bm * 128 + (lr2 >> 4) * 64 + i * 16 + (lr2 & 15);
      short* dst = chunked ? out + (size_t)bn * M * 256 + rowg * 256 + c
                           : out + rowg * (size_t)N + bn * 256 + c;
      *(short8*)dst = v;
    }
  }
}

// ---------------- fused attention: one block per (b, h, 64 q-rows) ------------------
__global__ __launch_bounds__(256) void attn_kernel(
    const short* __restrict__ qg, const short* __restrict__ kg, const short* __restrict__ vg,
    const int* __restrict__ ids, short* __restrict__ ctxg) {
  __shared__ short lds[32768];
  const int tid = threadIdx.x, lane = tid & 63, w = tid >> 6;
  const int lane15 = lane & 15, quad = lane >> 4;
  const int bx = blockIdx.x;
  const int qt = bx & 3, h = (bx >> 2) & 3, b = bx >> 4;
  const int base_row = b * SQ;
  const int hcol = h * DHQ;

  for (int it = 0; it < 8; ++it) {
    int s = it * 32 + (tid >> 3);
    int d0 = (tid & 7) * 8;
    size_t goff = (size_t)(base_row + s) * DQ + hcol + d0;
    intx4 kv = *(const intx4*)(kg + goff);
    *(intx4*)&lds[(d0 >> 5) * 8192 + s * 32 + (d0 & 31)] = kv;
    short8 vv = *(const short8*)(vg + goff);
    int vb0 = 16384 + (s >> 5) * 2048 + (s & 31);
#pragma unroll
    for (int i = 0; i < 8; ++i) lds[vb0 + (d0 + i) * 32] = vv[i];
  }
  __syncthreads();

  const int q0 = qt * 64 + w * 16;
  short8 qf[2];
#pragma unroll
  for (int ks = 0; ks < 2; ++ks)
    qf[ks] = *(const short8*)(qg + (size_t)(base_row + q0 + lane15) * DQ + hcol + ks * 32 + quad * 8);

  float sc[16][4];
#pragma unroll
  for (int t = 0; t < 16; ++t) {
    floatx4 a = {0.f, 0.f, 0.f, 0.f};
#pragma unroll
    for (int ks = 0; ks < 2; ++ks) {
      short8 bfr = *(const short8*)&lds[ks * 8192 + (t * 16 + lane15) * 32 + quad * 8];
      a = __builtin_amdgcn_mfma_f32_16x16x32_bf16(qf[ks], bfr, a, 0, 0, 0);
    }
    int kk = t * 16 + lane15;
    int padv = ids[base_row + kk];
#pragma unroll
    for (int r = 0; r < 4; ++r) {
      int q = q0 + quad * 4 + r;
      float bias = (padv > 0 && kk <= q) ? 0.0f : -10000.0f;
      sc[t][r] = a[r] * 0.125f + bias;
    }
  }
  __syncthreads();

#pragma unroll
  for (int r = 0; r < 4; ++r) {
    float m = -1e30f;
#pragma unroll
    for (int t = 0; t < 16; ++t) m = fmaxf(m, sc[t][r]);
    m = fmaxf(m, __shfl_xor(m, 1)); m = fmaxf(m, __shfl_xor(m, 2));
    m = fmaxf(m, __shfl_xor(m, 4)); m = fmaxf(m, __shfl_xor(m, 8));
    float l = 0.0f;
#pragma unroll
    for (int t = 0; t < 16; ++t) { sc[t][r] = __expf(sc[t][r] - m); l += sc[t][r]; }
    l += __shfl_xor(l, 1); l += __shfl_xor(l, 2);
    l += __shfl_xor(l, 4); l += __shfl_xor(l, 8);
    float inv = 1.0f / l;
#pragma unroll
    for (int t = 0; t < 16; ++t)
      lds[w * 4096 + (t >> 1) * 512 + (quad * 4 + r) * 32 + (t & 1) * 16 + lane15] =
          f2bf(sc[t][r] * inv);
  }
  __syncthreads();

  floatx4 o[4] = {};
#pragma unroll
  for (int kb = 0; kb < 8; ++kb) {
    short8 pf = *(const short8*)&lds[w * 4096 + kb * 512 + lane15 * 32 + quad * 8];
#pragma unroll
    for (int dt = 0; dt < 4; ++dt) {
      short8 vf = *(const short8*)&lds[16384 + kb * 2048 + (dt * 16 + lane15) * 32 + quad * 8];
      o[dt] = __builtin_amdgcn_mfma_f32_16x16x32_bf16(pf, vf, o[dt], 0, 0, 0);
    }
  }
#pragma unroll
  for (int dt = 0; dt < 4; ++dt)
#pragma unroll
    for (int r = 0; r < 4; ++r) {
      int q = q0 + quad * 4 + r;
      ctxg[(size_t)(base_row + q) * DQ + hcol + dt * 16 + lane15] = f2bf(o[dt][r]);
    }
}

extern "C" void kernel_launch(void* const* d_in, const int* in_sizes, int n_in,
                              void* d_out, int out_size, void* d_ws, size_t ws_size,
                              hipStream_t stream) {
  const int*   ids  = (const int*)d_in[0];
  const float* item = (const float*)d_in[1];
  const float* pos  = (const float*)d_in[2];
  const float* Wq = (const float*)d_in[3];  const float* bq = (const float*)d_in[4];
  const float* Wk = (const float*)d_in[5];  const float* bk = (const float*)d_in[6];
  const float* Wv = (const float*)d_in[7];  const float* bv = (const float*)d_in[8];
  const float* Wo = (const float*)d_in[9];  const float* bo = (const float*)d_in[10];
  const float* W1 = (const float*)d_in[11]; const float* b1 = (const float*)d_in[12];
  const float* W2 = (const float*)d_in[13]; const float* b2 = (const float*)d_in[14];
  float* out = (float*)d_out;

  const size_t EL = (size_t)BQ * SQ * DQ;   // 16,777,216
  short* qb    = (short*)d_ws;
  short* kb    = qb + EL;
  short* vb    = kb + EL;
  short* ctxb  = vb + EL;
  short* gb    = qb;                        // [M,1024] aliases q/k/v/ctx (all dead then)
  short* xb    = ctxb + EL;
  short* hb    = xb + EL;
  short* WqkvT = hb + EL;                   // [L][3][256][256]
  short* WoT   = WqkvT + 2 * 3 * 65536;     // [L][256][256]
  short* W1T   = WoT + 2 * 65536;           // [L][1024][256]
  short* W2T   = W1T + 2 * 262144;          // [L][256][1024]
  float* bqkv  = (float*)(W2T + 2 * 262144);// [L][768]

  const int M = BQ * SQ;                    // 65536

  for (int l = 0; l < 2; ++l) {
    wconv_kernel<<<256, 256, 0, stream>>>(Wq + l * 65536, WqkvT + (l * 3 + 0) * 65536, 256, 256, 65536);
    wconv_kernel<<<256, 256, 0, stream>>>(Wk + l * 65536, WqkvT + (l * 3 + 1) * 65536, 256, 256, 65536);
    wconv_kernel<<<256, 256, 0, stream>>>(Wv + l * 65536, WqkvT + (l * 3 + 2) * 65536, 256, 256, 65536);
  }
  wconv_kernel<<<512, 256, 0, stream>>>(Wo, WoT, 256, 256, 131072);
  wconv_kernel<<<2048, 256, 0, stream>>>(W1, W1T, 256, 1024, 524288);
  wconv_kernel<<<2048, 256, 0, stream>>>(W2, W2T, 1024, 256, 524288);
  bconv_kernel<<<6, 256, 0, stream>>>(bq, bk, bv, bqkv);

  embed_kernel<<<M / 4, 256, 0, stream>>>(ids, item, pos, xb, out);

  for (int l = 0; l < 2; ++l) {
    // fused QKV: N=768, chunked output -> qb/kb/vb
    gemm_kernel<<<dim3(3, M / 128), 512, 0, stream>>>(
        xb, WqkvT + (size_t)l * 3 * 65536, bqkv + l * 768, nullptr, qb, nullptr,
        M, 768, 256, 0, 0, 1);
    attn_kernel<<<BQ * HQ * (SQ / 64), 256, 0, stream>>>(qb, kb, vb, ids, ctxb);
    // Wo: +res(xb), LN -> hb
    gemm_kernel<<<dim3(1, M / 128), 512, 0, stream>>>(
        ctxb, WoT + (size_t)l * 65536, bo + l * 256, xb, hb, nullptr,
        M, 256, 256, 0, 1, 0);
    // W1: gelu -> gb
    gemm_kernel<<<dim3(4, M / 128), 512, 0, stream>>>(
        hb, W1T + (size_t)l * 262144, b1 + l * 1024, nullptr, gb, nullptr,
        M, 1024, 256, 1, 0, 0);
    // W2: LN -> xb, tot += y
    gemm_kernel<<<dim3(1, M / 128), 512, 0, stream>>>(
        gb, W2T + (size_t)l * 262144, b2 + l * 256, nullptr, xb, out,
        M, 256, 1024, 0, 1, 0);
  }
}